// Round 2
// baseline (761.788 us; speedup 1.0000x reference)
//
#include <hip/hip_runtime.h>
#include <cstdint>
#include <cstddef>

#define LRELU_ALPHA 0.2f

// N=4096, F_in=F_out=64, E=8, rows-per-block R=4
// Block = 256 threads = 4 waves. Wave w owns j in {w*64+l+256k : k<16, l<64}.
// R4: ef double-buffered in registers with one-chunk prefetch distance
// (predicated on the prefetched adj), adj prefetched two chunks ahead.
// Theory: ef was issued+consumed in the same chunk -> ~128 B/wave in flight
// over ~900cy HBM latency -> ~1.4 TB/s effective (latency-bound, ~330us).
// Prefetching puts the ef latency under the 64-iter accumulate -> BW-bound.
// a3/s1r forced to SGPRs via readfirstlane to keep VGPRs <= 128 (4 waves/EU).

typedef float f4 __attribute__((ext_vector_type(4)));

__device__ __forceinline__ f4 nt4(const float* p) {
    return __builtin_nontemporal_load((const f4*)p);
}

__device__ __forceinline__ float sbcast(float v) {
    // wave-uniform value -> SGPR
    return __int_as_float(__builtin_amdgcn_readfirstlane(__float_as_int(v)));
}

__global__ __launch_bounds__(256) void gat_prep(
    const float* __restrict__ x, const float* __restrict__ W,
    const float* __restrict__ a, float* __restrict__ h,
    float* __restrict__ s1, float* __restrict__ s2)
{
    __shared__ float Wl[64 * 64];
    const int tid = threadIdx.x;
    for (int idx = tid; idx < 64 * 64; idx += 256) Wl[idx] = W[idx];
    __syncthreads();

    const int wave = tid >> 6;
    const int lane = tid & 63;
    const int i = blockIdx.x * 4 + wave;   // one wave per row

    const float xv = x[i * 64 + lane];
    float hv = 0.f;
#pragma unroll
    for (int k = 0; k < 64; ++k)
        hv = fmaf(__shfl(xv, k), Wl[k * 64 + lane], hv);
    h[i * 64 + lane] = hv;

    float v1 = hv * a[lane];        // a1[f]
    float v2 = hv * a[64 + lane];   // a2[f]
#pragma unroll
    for (int off = 32; off >= 1; off >>= 1) {
        v1 += __shfl_xor(v1, off);
        v2 += __shfl_xor(v2, off);
    }
    if (lane == 0) { s1[i] = v1; s2[i] = v2; }
}

__device__ __forceinline__ float bcast(float v, int l) {
    return __int_as_float(__builtin_amdgcn_readlane(__float_as_int(v), l));
}

__global__ __launch_bounds__(256, 4) void gat_attn(
    const float* __restrict__ ef, const int* __restrict__ adj,
    const float* __restrict__ a, const float* __restrict__ h,
    const float* __restrict__ s1, const float* __restrict__ s2,
    float* __restrict__ out)
{
    __shared__ float accs[4][4][64];   // [wave][r][f] partial P@h
    __shared__ float lsums[4][4];      // [wave][r]   partial denominators

    const int tid  = threadIdx.x;
    const int w    = tid >> 6;
    const int lane = tid & 63;
    const int i0   = blockIdx.x * 4;

    // wave-uniform scalars -> SGPRs (saves 12 VGPRs vs R3)
    float a3[8];
#pragma unroll
    for (int e = 0; e < 8; ++e) a3[e] = sbcast(a[128 + e]);

    float s1r[4];
#pragma unroll
    for (int r = 0; r < 4; ++r) s1r[r] = sbcast(s1[i0 + r]);

    float acc0 = 0.f, acc1 = 0.f, acc2 = 0.f, acc3 = 0.f;
    float ls0 = 0.f, ls1 = 0.f, ls2 = 0.f, ls3 = 0.f;

    const size_t efrow = (size_t)4096 * 8;
    const float* __restrict__ efr[4];
#pragma unroll
    for (int r = 0; r < 4; ++r) efr[r] = ef + (size_t)(i0 + r) * efrow;

    // --- prologue: adj(0), ef(0) predicated on adj(0), adj(1) ---
    int ad[4], adn[4];
#pragma unroll
    for (int r = 0; r < 4; ++r)
        ad[r] = __builtin_nontemporal_load(adj + (size_t)(i0 + r) * 4096 + tid);

    f4 ec0[4], ec1[4];                 // current-chunk ef registers
#pragma unroll
    for (int r = 0; r < 4; ++r) {
        if (ad[r] > 0) {
            const float* efp = efr[r] + (size_t)tid * 8;
            ec0[r] = nt4(efp);
            ec1[r] = nt4(efp + 4);
        }
    }
#pragma unroll
    for (int r = 0; r < 4; ++r)
        adn[r] = __builtin_nontemporal_load(
            adj + (size_t)(i0 + r) * 4096 + tid + 256);

    for (int k = 0; k < 16; ++k) {
        const int j = tid + (k << 8);          // this thread's column
        const float s2j = s2[j];

        // --- scores -> p for 4 rows at column j, from prefetched ec ---
        float p0, p1, p2, p3;
        {
            float pv[4];
#pragma unroll
            for (int r = 0; r < 4; ++r) {
                float p = 0.f;
                if (ad[r] > 0) {
                    const f4 e0 = ec0[r];
                    const f4 e1 = ec1[r];
                    float s3 = e0.x * a3[0] + e0.y * a3[1] + e0.z * a3[2] + e0.w * a3[3]
                             + e1.x * a3[4] + e1.y * a3[5] + e1.z * a3[6] + e1.w * a3[7];
                    float e = s1r[r] + s2j + s3;
                    e = (e > 0.f) ? e : LRELU_ALPHA * e;
                    p = __expf(e);
                }
                pv[r] = p;                      // masked -> exactly 0
            }
            p0 = pv[0]; p1 = pv[1]; p2 = pv[2]; p3 = pv[3];
        }
        ls0 += p0; ls1 += p1; ls2 += p2; ls3 += p3;

        // --- prefetch ef(k+1), predicated on adn (issued one chunk ago,
        // already arrived). Latency hides under the accumulate below. ---
        f4 en0[4], en1[4];
        if (k < 15) {
            const int jn = j + 256;
#pragma unroll
            for (int r = 0; r < 4; ++r) {
                if (adn[r] > 0) {
                    const float* efp = efr[r] + (size_t)jn * 8;
                    en0[r] = nt4(efp);
                    en1[r] = nt4(efp + 4);
                }
            }
        }
        // --- prefetch adj(k+2) ---
        int ad2[4];
        if (k < 14) {
#pragma unroll
            for (int r = 0; r < 4; ++r)
                ad2[r] = __builtin_nontemporal_load(
                    adj + (size_t)(i0 + r) * 4096 + j + 512);
        }

        // --- wave-local rank-1 accumulate: lane = output feature f ---
        const int jw0 = (w << 6) + (k << 8);   // wave w's 64 columns start
        const float* __restrict__ hp = h + (size_t)jw0 * 64 + lane;
#pragma unroll 8
        for (int l = 0; l < 64; ++l) {
            const float hv = hp[l * 64];       // coalesced 256 B / wave, L2-hot
            acc0 = fmaf(bcast(p0, l), hv, acc0);
            acc1 = fmaf(bcast(p1, l), hv, acc1);
            acc2 = fmaf(bcast(p2, l), hv, acc2);
            acc3 = fmaf(bcast(p3, l), hv, acc3);
        }

        // --- rotate prefetch registers ---
#pragma unroll
        for (int r = 0; r < 4; ++r) {
            ad[r]  = adn[r];
            adn[r] = ad2[r];
            ec0[r] = en0[r];
            ec1[r] = en1[r];
        }
    }

    // --- wave-reduce the denominators ---
#pragma unroll
    for (int off = 32; off >= 1; off >>= 1) {
        ls0 += __shfl_xor(ls0, off);
        ls1 += __shfl_xor(ls1, off);
        ls2 += __shfl_xor(ls2, off);
        ls3 += __shfl_xor(ls3, off);
    }
    if (lane == 0) {
        lsums[w][0] = ls0; lsums[w][1] = ls1;
        lsums[w][2] = ls2; lsums[w][3] = ls3;
    }
    accs[w][0][lane] = acc0;
    accs[w][1][lane] = acc1;
    accs[w][2][lane] = acc2;
    accs[w][3][lane] = acc3;
    __syncthreads();                           // the block's ONLY barrier

    // --- wave w finalizes row i0+w; lane = f ---
    const float v = accs[0][w][lane] + accs[1][w][lane]
                  + accs[2][w][lane] + accs[3][w][lane];
    const float S = lsums[0][w] + lsums[1][w] + lsums[2][w] + lsums[3][w];
    float o = v / S;
    o = (o > 0.f) ? o : (__expf(o) - 1.f);     // ELU (alpha=1)
    out[(size_t)(i0 + w) * 64 + lane] = o;
}

extern "C" void kernel_launch(void* const* d_in, const int* in_sizes, int n_in,
                              void* d_out, int out_size, void* d_ws, size_t ws_size,
                              hipStream_t stream) {
    const float* x   = (const float*)d_in[0];   // (4096, 64)
    const int*   adj = (const int*)  d_in[1];   // (4096, 4096)
    const float* ef  = (const float*)d_in[2];   // (4096, 4096, 8)
    const float* W   = (const float*)d_in[3];   // (64, 64)
    const float* a   = (const float*)d_in[4];   // (136, 1)
    float* out = (float*)d_out;                 // (4096, 64)

    float* h  = (float*)d_ws;                   // 4096*64 floats
    float* s1 = h + 4096 * 64;                  // 4096 floats
    float* s2 = s1 + 4096;                      // 4096 floats

    gat_prep<<<1024, 256, 0, stream>>>(x, W, a, h, s1, s2);
    gat_attn<<<1024, 256, 0, stream>>>(ef, adj, a, h, s1, s2, out);
}

// Round 3
// 757.642 us; speedup vs baseline: 1.0055x; 1.0055x over previous
//
#include <hip/hip_runtime.h>
#include <cstdint>
#include <cstddef>

#define LRELU_ALPHA 0.2f

// N=4096, F_in=F_out=64, E=8, rows-per-block R=4
// Block = 256 threads = 4 waves. Wave w owns j in {w*64+l+256k : k<16, l<64}.
// R5: counter-correct software pipeline.
//  - ef/adj loads UNCONDITIONAL (wrapped tail addrs) -> static vmcnt counts;
//    adjacency only gates a select of p (cndmask), not the load.
//  - per chunk, issue order is: h-loads->regs, THEN ef(k+1)/adj(k+2), THEN fma.
//    vmcnt retires in order, so with ef youngest the fma loop waits only on h
//    (vmcnt(12)), and ef gets the whole fma phase (~1000+cy) to cover its
//    ~900cy HBM latency; consumed next chunk at vmcnt(4).
//  - sched_barrier(0) fences pin the three regions against LLVM reordering.
//  - s2 staged in LDS (lgkmcnt path, keeps vmcnt clean); a3/s1r in SGPRs;
//    h chunk in 64 VGPRs. Budget ~125 VGPR at 4 waves/EU.

typedef float f4 __attribute__((ext_vector_type(4)));

__device__ __forceinline__ f4 nt4(const float* p) {
    return __builtin_nontemporal_load((const f4*)p);
}

__device__ __forceinline__ float sbcast(float v) {
    // wave-uniform value -> SGPR
    return __int_as_float(__builtin_amdgcn_readfirstlane(__float_as_int(v)));
}

__device__ __forceinline__ float bcast(float v, int l) {
    return __int_as_float(__builtin_amdgcn_readlane(__float_as_int(v), l));
}

__global__ __launch_bounds__(256) void gat_prep(
    const float* __restrict__ x, const float* __restrict__ W,
    const float* __restrict__ a, float* __restrict__ h,
    float* __restrict__ s1, float* __restrict__ s2)
{
    __shared__ float Wl[64 * 64];
    const int tid = threadIdx.x;
    for (int idx = tid; idx < 64 * 64; idx += 256) Wl[idx] = W[idx];
    __syncthreads();

    const int wave = tid >> 6;
    const int lane = tid & 63;
    const int i = blockIdx.x * 4 + wave;   // one wave per row

    const float xv = x[i * 64 + lane];
    float hv = 0.f;
#pragma unroll
    for (int k = 0; k < 64; ++k)
        hv = fmaf(__shfl(xv, k), Wl[k * 64 + lane], hv);
    h[i * 64 + lane] = hv;

    float v1 = hv * a[lane];        // a1[f]
    float v2 = hv * a[64 + lane];   // a2[f]
#pragma unroll
    for (int off = 32; off >= 1; off >>= 1) {
        v1 += __shfl_xor(v1, off);
        v2 += __shfl_xor(v2, off);
    }
    if (lane == 0) { s1[i] = v1; s2[i] = v2; }
}

__global__ __launch_bounds__(256, 4) void gat_attn(
    const float* __restrict__ ef, const int* __restrict__ adj,
    const float* __restrict__ a, const float* __restrict__ h,
    const float* __restrict__ s1, const float* __restrict__ s2,
    float* __restrict__ out)
{
    __shared__ float s2l[4096];        // s2 table: read via lgkmcnt, not vmcnt
    __shared__ float accs[4][4][64];   // [wave][r][f] partial P@h
    __shared__ float lsums[4][4];      // [wave][r]   partial denominators

    const int tid  = threadIdx.x;
    const int w    = tid >> 6;
    const int lane = tid & 63;
    const int i0   = blockIdx.x * 4;

    // stage s2 into LDS (one-time, 16 KB)
    for (int t = tid; t < 4096; t += 256) s2l[t] = s2[t];

    // wave-uniform scalars -> SGPRs
    float a3[8];
#pragma unroll
    for (int e = 0; e < 8; ++e) a3[e] = sbcast(a[128 + e]);
    float s1r[4];
#pragma unroll
    for (int r = 0; r < 4; ++r) s1r[r] = sbcast(s1[i0 + r]);

    __syncthreads();

    const size_t efrow = (size_t)4096 * 8;
    const float* __restrict__ ef0 = ef + (size_t)(i0 + 0) * efrow;
    const float* __restrict__ ef1 = ef + (size_t)(i0 + 1) * efrow;
    const float* __restrict__ ef2 = ef + (size_t)(i0 + 2) * efrow;
    const float* __restrict__ ef3 = ef + (size_t)(i0 + 3) * efrow;
    const int* __restrict__ aj0 = adj + (size_t)(i0 + 0) * 4096;
    const int* __restrict__ aj1 = adj + (size_t)(i0 + 1) * 4096;
    const int* __restrict__ aj2 = adj + (size_t)(i0 + 2) * 4096;
    const int* __restrict__ aj3 = adj + (size_t)(i0 + 3) * 4096;

    float acc0 = 0.f, acc1 = 0.f, acc2 = 0.f, acc3 = 0.f;
    float ls0 = 0.f, ls1 = 0.f, ls2 = 0.f, ls3 = 0.f;

    // --- prologue: adj(0), adj(1), ef(0) --- all unconditional
    int ad[4], adn[4];
    ad[0] = __builtin_nontemporal_load(aj0 + tid);
    ad[1] = __builtin_nontemporal_load(aj1 + tid);
    ad[2] = __builtin_nontemporal_load(aj2 + tid);
    ad[3] = __builtin_nontemporal_load(aj3 + tid);
    adn[0] = __builtin_nontemporal_load(aj0 + tid + 256);
    adn[1] = __builtin_nontemporal_load(aj1 + tid + 256);
    adn[2] = __builtin_nontemporal_load(aj2 + tid + 256);
    adn[3] = __builtin_nontemporal_load(aj3 + tid + 256);

    f4 ec0[4], ec1[4];
    {
        const size_t o = (size_t)tid * 8;
        ec0[0] = nt4(ef0 + o); ec1[0] = nt4(ef0 + o + 4);
        ec0[1] = nt4(ef1 + o); ec1[1] = nt4(ef1 + o + 4);
        ec0[2] = nt4(ef2 + o); ec1[2] = nt4(ef2 + o + 4);
        ec0[3] = nt4(ef3 + o); ec1[3] = nt4(ef3 + o + 4);
    }

    for (int k = 0; k < 16; ++k) {
        const int j = tid + (k << 8);          // this thread's column
        const float s2j = s2l[j];              // ds_read (lgkmcnt)

        // --- 1. scores -> p from prefetched ec; mask via select, no branch ---
        float p0, p1, p2, p3;
        {
            float pv[4];
#pragma unroll
            for (int r = 0; r < 4; ++r) {
                const f4 e0 = ec0[r];
                const f4 e1 = ec1[r];
                float s3 = e0.x * a3[0] + e0.y * a3[1] + e0.z * a3[2] + e0.w * a3[3]
                         + e1.x * a3[4] + e1.y * a3[5] + e1.z * a3[6] + e1.w * a3[7];
                float e = s1r[r] + s2j + s3;
                e = (e > 0.f) ? e : LRELU_ALPHA * e;
                pv[r] = (ad[r] > 0) ? __expf(e) : 0.f;
            }
            p0 = pv[0]; p1 = pv[1]; p2 = pv[2]; p3 = pv[3];
        }
        ls0 += p0; ls1 += p1; ls2 += p2; ls3 += p3;

        // --- 2. issue this chunk's h-loads into registers (oldest) ---
        float hreg[64];
        const float* __restrict__ hp = h + (size_t)((w << 6) + (k << 8)) * 64 + lane;
#pragma unroll
        for (int l = 0; l < 64; ++l) hreg[l] = hp[l * 64];

        __builtin_amdgcn_sched_barrier(0);

        // --- 3. issue ef(k+1) and adj(k+2) prefetch (youngest; wrapped tail) ---
        {
            const int jn = (j + 256) & 4095;
            const size_t o = (size_t)jn * 8;
            ec0[0] = nt4(ef0 + o); ec1[0] = nt4(ef0 + o + 4);
            ec0[1] = nt4(ef1 + o); ec1[1] = nt4(ef1 + o + 4);
            ec0[2] = nt4(ef2 + o); ec1[2] = nt4(ef2 + o + 4);
            ec0[3] = nt4(ef3 + o); ec1[3] = nt4(ef3 + o + 4);
        }
        int ad2[4];
        {
            const int j2 = (j + 512) & 4095;
            ad2[0] = __builtin_nontemporal_load(aj0 + j2);
            ad2[1] = __builtin_nontemporal_load(aj1 + j2);
            ad2[2] = __builtin_nontemporal_load(aj2 + j2);
            ad2[3] = __builtin_nontemporal_load(aj3 + j2);
        }

        __builtin_amdgcn_sched_barrier(0);

        // --- 4. fma: consumes hreg (waits only vmcnt(12), never on ef) ---
#pragma unroll
        for (int l = 0; l < 64; ++l) {
            const float hv = hreg[l];
            acc0 = fmaf(bcast(p0, l), hv, acc0);
            acc1 = fmaf(bcast(p1, l), hv, acc1);
            acc2 = fmaf(bcast(p2, l), hv, acc2);
            acc3 = fmaf(bcast(p3, l), hv, acc3);
        }

        // --- 5. rotate adj ---
#pragma unroll
        for (int r = 0; r < 4; ++r) { ad[r] = adn[r]; adn[r] = ad2[r]; }
    }

    // --- wave-reduce the denominators ---
#pragma unroll
    for (int off = 32; off >= 1; off >>= 1) {
        ls0 += __shfl_xor(ls0, off);
        ls1 += __shfl_xor(ls1, off);
        ls2 += __shfl_xor(ls2, off);
        ls3 += __shfl_xor(ls3, off);
    }
    if (lane == 0) {
        lsums[w][0] = ls0; lsums[w][1] = ls1;
        lsums[w][2] = ls2; lsums[w][3] = ls3;
    }
    accs[w][0][lane] = acc0;
    accs[w][1][lane] = acc1;
    accs[w][2][lane] = acc2;
    accs[w][3][lane] = acc3;
    __syncthreads();

    // --- wave w finalizes row i0+w; lane = f ---
    const float v = accs[0][w][lane] + accs[1][w][lane]
                  + accs[2][w][lane] + accs[3][w][lane];
    const float S = lsums[0][w] + lsums[1][w] + lsums[2][w] + lsums[3][w];
    float o = v / S;
    o = (o > 0.f) ? o : (__expf(o) - 1.f);     // ELU (alpha=1)
    out[(size_t)(i0 + w) * 64 + lane] = o;
}

extern "C" void kernel_launch(void* const* d_in, const int* in_sizes, int n_in,
                              void* d_out, int out_size, void* d_ws, size_t ws_size,
                              hipStream_t stream) {
    const float* x   = (const float*)d_in[0];   // (4096, 64)
    const int*   adj = (const int*)  d_in[1];   // (4096, 4096)
    const float* ef  = (const float*)d_in[2];   // (4096, 4096, 8)
    const float* W   = (const float*)d_in[3];   // (64, 64)
    const float* a   = (const float*)d_in[4];   // (136, 1)
    float* out = (float*)d_out;                 // (4096, 64)

    float* h  = (float*)d_ws;                   // 4096*64 floats
    float* s1 = h + 4096 * 64;                  // 4096 floats
    float* s2 = s1 + 4096;                      // 4096 floats

    gat_prep<<<1024, 256, 0, stream>>>(x, W, a, h, s1, s2);
    gat_attn<<<1024, 256, 0, stream>>>(ef, adj, a, h, s1, s2, out);
}

// Round 4
// 739.067 us; speedup vs baseline: 1.0307x; 1.0251x over previous
//
#include <hip/hip_runtime.h>
#include <cstdint>
#include <cstddef>

#define LRELU_ALPHA 0.2f

// N=4096, F_in=F_out=64, E=8
// R6: rows-per-block R=8, block = 512 threads = 8 waves, grid = 512 blocks.
// Rationale: R4/R5 pipeline experiments were both null -> attn is NOT
// ef-latency-bound (4 waves/SIMD TLP already hides ~900cy under ~4900cy of
// resident VALU work). Remaining floors: h L2 re-read (1 MB x nblocks = 1 GB
// at ~135 GB/s/CU ~= 120us) and the ef HBM stream (~90-110us). h-traffic per
// block is independent of R, so R=8 halves total h L2 traffic (1 GB->512 MB).
// ef loads predicated again (saves HBM sectors where both j's of a line mask;
// latency covered by TLP). Same 16 waves/CU occupancy (2 blocks/CU).

typedef float f4 __attribute__((ext_vector_type(4)));

__device__ __forceinline__ f4 nt4(const float* p) {
    return __builtin_nontemporal_load((const f4*)p);
}

__device__ __forceinline__ float sbcast(float v) {
    // wave-uniform value -> SGPR
    return __int_as_float(__builtin_amdgcn_readfirstlane(__float_as_int(v)));
}

__device__ __forceinline__ float bcast(float v, int l) {
    return __int_as_float(__builtin_amdgcn_readlane(__float_as_int(v), l));
}

__global__ __launch_bounds__(256) void gat_prep(
    const float* __restrict__ x, const float* __restrict__ W,
    const float* __restrict__ a, float* __restrict__ h,
    float* __restrict__ s1, float* __restrict__ s2)
{
    __shared__ float Wl[64 * 64];
    const int tid = threadIdx.x;
    for (int idx = tid; idx < 64 * 64; idx += 256) Wl[idx] = W[idx];
    __syncthreads();

    const int wave = tid >> 6;
    const int lane = tid & 63;
    const int i = blockIdx.x * 4 + wave;   // one wave per row

    const float xv = x[i * 64 + lane];
    float hv = 0.f;
#pragma unroll
    for (int k = 0; k < 64; ++k)
        hv = fmaf(__shfl(xv, k), Wl[k * 64 + lane], hv);
    h[i * 64 + lane] = hv;

    float v1 = hv * a[lane];        // a1[f]
    float v2 = hv * a[64 + lane];   // a2[f]
#pragma unroll
    for (int off = 32; off >= 1; off >>= 1) {
        v1 += __shfl_xor(v1, off);
        v2 += __shfl_xor(v2, off);
    }
    if (lane == 0) { s1[i] = v1; s2[i] = v2; }
}

__global__ __launch_bounds__(512, 4) void gat_attn(
    const float* __restrict__ ef, const int* __restrict__ adj,
    const float* __restrict__ a, const float* __restrict__ h,
    const float* __restrict__ s1, const float* __restrict__ s2,
    float* __restrict__ out)
{
    __shared__ float s2l[4096];        // s2 table (16 KB, lgkmcnt path)
    __shared__ float accs[8][8][64];   // [wave][r][f] partial P@h (16 KB)
    __shared__ float lsums[8][8];      // [wave][r]   partial denominators

    const int tid  = threadIdx.x;      // 0..511
    const int w    = tid >> 6;         // 0..7
    const int lane = tid & 63;
    const int i0   = blockIdx.x * 8;

    for (int t = tid; t < 4096; t += 512) s2l[t] = s2[t];

    // wave-uniform scalars -> SGPRs
    float a3[8];
#pragma unroll
    for (int e = 0; e < 8; ++e) a3[e] = sbcast(a[128 + e]);
    float s1r[8];
#pragma unroll
    for (int r = 0; r < 8; ++r) s1r[r] = sbcast(s1[i0 + r]);

    __syncthreads();

    const size_t efrow = (size_t)4096 * 8;

    float acc[8], ls[8];
#pragma unroll
    for (int r = 0; r < 8; ++r) { acc[r] = 0.f; ls[r] = 0.f; }

    // adj for chunk 0 (nontemporal: adj is streamed exactly once)
    int ad[8];
#pragma unroll
    for (int r = 0; r < 8; ++r)
        ad[r] = __builtin_nontemporal_load(adj + (size_t)(i0 + r) * 4096 + tid);

    for (int k = 0; k < 8; ++k) {
        const int j = tid + (k << 9);          // this thread's column
        const float s2j = s2l[j];

        // prefetch adj for chunk k+1 (consumed only at loop end -> in flight)
        int adn[8];
        if (k < 7) {
#pragma unroll
            for (int r = 0; r < 8; ++r)
                adn[r] = __builtin_nontemporal_load(
                    adj + (size_t)(i0 + r) * 4096 + j + 512);
        }

        // --- scores -> p for 8 rows at column j; ef loads predicated on
        // adj>0 (masked lanes fetch nothing); TLP hides the latency ---
        float p[8];
#pragma unroll
        for (int r = 0; r < 8; ++r) {
            float pp = 0.f;
            if (ad[r] > 0) {
                const float* efp = ef + (size_t)(i0 + r) * efrow + (size_t)j * 8;
                const f4 e0 = nt4(efp);
                const f4 e1 = nt4(efp + 4);
                float s3 = e0.x * a3[0] + e0.y * a3[1] + e0.z * a3[2] + e0.w * a3[3]
                         + e1.x * a3[4] + e1.y * a3[5] + e1.z * a3[6] + e1.w * a3[7];
                float e = s1r[r] + s2j + s3;
                e = (e > 0.f) ? e : LRELU_ALPHA * e;
                pp = __expf(e);
            }
            p[r] = pp;                          // masked -> exactly 0
            ls[r] += pp;
        }

        // --- wave-local rank-1 accumulate: lane = output feature f ---
        const int jw0 = (w << 6) + (k << 9);   // wave w's 64 columns start
        const float* __restrict__ hp = h + (size_t)jw0 * 64 + lane;
#pragma unroll 8
        for (int l = 0; l < 64; ++l) {
            const float hv = hp[l * 64];       // coalesced 256 B / wave, L2-hot
#pragma unroll
            for (int r = 0; r < 8; ++r)
                acc[r] = fmaf(bcast(p[r], l), hv, acc[r]);
        }

#pragma unroll
        for (int r = 0; r < 8; ++r) ad[r] = adn[r];
    }

    // --- wave-reduce the denominators ---
#pragma unroll
    for (int off = 32; off >= 1; off >>= 1) {
#pragma unroll
        for (int r = 0; r < 8; ++r) ls[r] += __shfl_xor(ls[r], off);
    }
    if (lane == 0) {
#pragma unroll
        for (int r = 0; r < 8; ++r) lsums[w][r] = ls[r];
    }
#pragma unroll
    for (int r = 0; r < 8; ++r) accs[w][r][lane] = acc[r];
    __syncthreads();                           // the block's ONLY barrier

    // --- wave w finalizes row i0+w; lane = f ---
    float v = 0.f, S = 0.f;
#pragma unroll
    for (int w2 = 0; w2 < 8; ++w2) {
        v += accs[w2][w][lane];
        S += lsums[w2][w];
    }
    float o = v / S;
    o = (o > 0.f) ? o : (__expf(o) - 1.f);     // ELU (alpha=1)
    out[(size_t)(i0 + w) * 64 + lane] = o;
}

extern "C" void kernel_launch(void* const* d_in, const int* in_sizes, int n_in,
                              void* d_out, int out_size, void* d_ws, size_t ws_size,
                              hipStream_t stream) {
    const float* x   = (const float*)d_in[0];   // (4096, 64)
    const int*   adj = (const int*)  d_in[1];   // (4096, 4096)
    const float* ef  = (const float*)d_in[2];   // (4096, 4096, 8)
    const float* W   = (const float*)d_in[3];   // (64, 64)
    const float* a   = (const float*)d_in[4];   // (136, 1)
    float* out = (float*)d_out;                 // (4096, 64)

    float* h  = (float*)d_ws;                   // 4096*64 floats
    float* s1 = h + 4096 * 64;                  // 4096 floats
    float* s2 = s1 + 4096;                      // 4096 floats

    gat_prep<<<1024, 256, 0, stream>>>(x, W, a, h, s1, s2);
    gat_attn<<<512, 512, 0, stream>>>(ef, adj, a, h, s1, s2, out);
}